// Round 11
// baseline (393.976 us; speedup 1.0000x reference)
//
#include <hip/hip_runtime.h>
#include <hip/hip_bf16.h>
#include <math.h>

constexpr int HS = 32;      // half spatial (32x32 grids)
constexpr int Lq = 1024;    // HS*HS
constexpr int CN = 128;     // channels
constexpr int KP = 1152;    // 128 * 3 * 3 patch length
// batches = 2. Inputs fp32, dict order (f, b, mask). OUTPUT FLOAT32 (reference returns
// fp32; the "bf16" in the checker label is a literal string — r10 probe exposed that my
// bf16 writes were being read as packed fp32, decorrelating everything).

// ---------------- prep: downsample to 32x32, channel-last fp32 ----------------
__global__ __launch_bounds__(256) void k_prep(const float* __restrict__ f,
                                              const float* __restrict__ bsrc,
                                              float* __restrict__ fdT, float* __restrict__ bdT) {
    int idx = blockIdx.x * 256 + threadIdx.x;        // [0, 262144)
    int c  = idx & (CN - 1);
    int p  = (idx >> 7) & (Lq - 1);
    int bb = idx >> 17;
    int py = p >> 5, px = p & 31;
    long src = (((long)bb * CN + c) * 64 + 2 * py) * 64 + 2 * px;
    fdT[idx] = f[src];
    bdT[idx] = bsrc[src];
}

// ---------------- mm[q] from mask batch 0 (3x3 patch mean == 0) ----------------
__global__ __launch_bounds__(256) void k_mm(const float* __restrict__ mask, float* __restrict__ mmb) {
    int q = blockIdx.x * 256 + threadIdx.x;  // 1024
    int qy = q >> 5, qx = q & 31;
    float s = 0.f;
    for (int dk = -1; dk <= 1; ++dk) {
        int y = qy + dk; if ((unsigned)y >= (unsigned)HS) continue;
        for (int dl = -1; dl <= 1; ++dl) {
            int x = qx + dl; if ((unsigned)x >= (unsigned)HS) continue;
            s += mask[(8 * y) * 256 + 8 * x];
        }
    }
    mmb[q] = (s == 0.0f) ? 1.0f : 0.0f;
}

// ---------------- literal patch extraction (k=3, s=1, pad 1), fp32 ----------------
// layout j = (k*3+l)*128 + c
__global__ __launch_bounds__(256) void k_patches(const float* __restrict__ fdT, const float* __restrict__ bdT,
                                                 float* __restrict__ fpP, float* __restrict__ wP) {
    int idx = blockIdx.x * 256 + threadIdx.x;   // [0, 2359296)
    int j = idx % KP;
    int t = idx / KP;
    int q = t & (Lq - 1);
    int bb = t >> 10;
    int c = j & 127, r = j >> 7;                // r in [0,9)
    int dk = r / 3 - 1, dl = r % 3 - 1;
    int y = (q >> 5) + dk, x = (q & 31) + dl;
    float vw = 0.f, vf = 0.f;
    if ((unsigned)y < (unsigned)HS && (unsigned)x < (unsigned)HS) {
        long s = ((long)((bb << 10) | (y * HS + x))) * CN + c;
        vw = bdT[s];
        vf = fdT[s];
    }
    wP[idx]  = vw;
    fpP[idx] = vf;
}

// ---------------- row norm fp32: normq = sqrt(sum w^2 + 0.1152) ----------------
__global__ __launch_bounds__(64) void k_rownorm(const float* __restrict__ wP, float* __restrict__ normq) {
    int row = blockIdx.x;                        // 0..2047 (b*1024+q)
    const float* rp = wP + (long)row * KP;
    float s = 0.f;
    for (int i = threadIdx.x; i < KP; i += 64) { float v = rp[i]; s += v * v; }
    for (int off = 32; off > 0; off >>= 1) s += __shfl_down(s, off, 64);
    if (threadIdx.x == 0) normq[row] = sqrtf(s + 0.1152f);
}

// ---------------- wn = w / norm in place ----------------
__global__ __launch_bounds__(256) void k_wn(float* __restrict__ wP, const float* __restrict__ normq) {
    int idx = blockIdx.x * 256 + threadIdx.x;    // 2359296
    int row = idx / KP;
    wP[idx] = wP[idx] / normq[row];
}

// ---------------- GEMM NT 64x64 tile, 4x4/thread: C[m][n] = sum_k A[m][k]*B[n][k] ----------------
__global__ __launch_bounds__(256) void k_gemm_nt64(const float* __restrict__ A, const float* __restrict__ B,
                                                   float* __restrict__ Cm, int Mdim, int Ndim, int Kdim) {
    const long bz = blockIdx.z;
    A  += bz * (long)Mdim * Kdim;
    B  += bz * (long)Ndim * Kdim;
    Cm += bz * (long)Mdim * Ndim;
    __shared__ __align__(16) float As[32][68];
    __shared__ __align__(16) float Bs[32][68];
    int tx = threadIdx.x;
    int m0 = blockIdx.x * 64, n0 = blockIdx.y * 64;
    int tr = tx >> 4, tc = tx & 15;
    int k4 = tx & 7, row = tx >> 3;
    float acc[4][4] = {};
    for (int k0 = 0; k0 < Kdim; k0 += 32) {
#pragma unroll
        for (int it = 0; it < 2; ++it) {
            int r = row + it * 32;
            float4 va = *(const float4*)&A[(long)(m0 + r) * Kdim + k0 + k4 * 4];
            As[k4 * 4 + 0][r] = va.x; As[k4 * 4 + 1][r] = va.y;
            As[k4 * 4 + 2][r] = va.z; As[k4 * 4 + 3][r] = va.w;
            float4 vb = *(const float4*)&B[(long)(n0 + r) * Kdim + k0 + k4 * 4];
            Bs[k4 * 4 + 0][r] = vb.x; Bs[k4 * 4 + 1][r] = vb.y;
            Bs[k4 * 4 + 2][r] = vb.z; Bs[k4 * 4 + 3][r] = vb.w;
        }
        __syncthreads();
#pragma unroll
        for (int k = 0; k < 32; ++k) {
            float4 a4 = *(const float4*)&As[k][tr * 4];
            float4 b4 = *(const float4*)&Bs[k][tc * 4];
            float a_[4] = {a4.x, a4.y, a4.z, a4.w};
            float b_[4] = {b4.x, b4.y, b4.z, b4.w};
#pragma unroll
            for (int i = 0; i < 4; ++i)
#pragma unroll
                for (int j = 0; j < 4; ++j) acc[i][j] += a_[i] * b_[j];
        }
        __syncthreads();
    }
#pragma unroll
    for (int i = 0; i < 4; ++i) {
        int m = m0 + tr * 4 + i;
        *(float4*)&Cm[(long)m * Ndim + n0 + tc * 4] =
            make_float4(acc[i][0], acc[i][1], acc[i][2], acc[i][3]);
    }
}

// ---------------- literal fuse_diag on flat (1024,1024) per batch (WRAP semantics) ----------------
__global__ __launch_bounds__(256) void k_fuse_flat(const float* __restrict__ src, float* __restrict__ dst) {
    int idx = blockIdx.x * 256 + threadIdx.x;
    int j = idx & (Lq - 1);
    int i = (idx >> 10) & (Lq - 1);
    float s = src[idx];
    if (i > 0 && j > 0)               s += src[idx - (Lq + 1)];
    if (i < Lq - 1 && j < Lq - 1)     s += src[idx + (Lq + 1)];
    dst[idx] = s;
}

// ---------------- transpose(1,0,3,2) of (32,32,32,32), materialized (exact) ----------------
__global__ __launch_bounds__(256) void k_t4(const float* __restrict__ src, float* __restrict__ dst) {
    int idx = blockIdx.x * 256 + threadIdx.x;
    int j = idx & (Lq - 1);
    int i = (idx >> 10) & (Lq - 1);
    int bb = idx >> 20;
    int si = ((i & 31) << 5) | (i >> 5);
    int sj = ((j & 31) << 5) | (j >> 5);
    dst[idx] = src[(((long)(bb << 10) | si) << 10) | sj];
}

// ---------------- softmax over q (stride-1024 axis), fp32, p coalesced ----------------
__global__ __launch_bounds__(512) void k_softmax(const float* __restrict__ S2, const float* __restrict__ mmb,
                                                 float* __restrict__ attn) {
    int p  = blockIdx.x * 64 + threadIdx.x;
    int bb = blockIdx.y;
    int ty = threadIdx.y;        // 0..7, each owns 128 q's
    const float* S = S2 + (long)bb * Lq * Lq;
    float* A = attn + (long)bb * Lq * Lq;
    __shared__ float red[8][64];
    int q0 = ty * 128;
    float mx = -1e30f;
    for (int qi = q0; qi < q0 + 128; ++qi) {
        float v = S[(long)qi * Lq + p] * mmb[qi] * 10.0f;
        mx = fmaxf(mx, v);
    }
    red[ty][threadIdx.x] = mx;
    __syncthreads();
    mx = red[0][threadIdx.x];
#pragma unroll
    for (int k = 1; k < 8; ++k) mx = fmaxf(mx, red[k][threadIdx.x]);
    __syncthreads();
    float s = 0.f;
    for (int qi = q0; qi < q0 + 128; ++qi) {
        float mq = mmb[qi];
        float v = S[(long)qi * Lq + p] * mq * 10.0f;
        float e = __expf(v - mx);
        A[(long)qi * Lq + p] = e * mq;   // numerator masked
        s += e;                          // denominator unmasked (matches ref)
    }
    red[ty][threadIdx.x] = s;
    __syncthreads();
    s = 0.f;
#pragma unroll
    for (int k = 0; k < 8; ++k) s += red[k][threadIdx.x];
    float inv = 1.0f / s;
    for (int qi = q0; qi < q0 + 128; ++qi) A[(long)qi * Lq + p] *= inv;
}

// ---------------- P[m=(c,u,v)][p] = sum_q wpat[q,c,u,v] * attn[q][p], fp32 ----------------
// wpat[q,c,u,v] = b[c, 2qy+u-1, 2qx+v-1] (k=4, s=2, pad 1) gathered on the fly.
__global__ __launch_bounds__(256) void k_gemm_gather(const float* __restrict__ bsrc,
                                                     const float* __restrict__ Bm, float* __restrict__ Cm) {
    const long bz = blockIdx.z;
    const float* B = Bm + bz * (long)Lq * Lq;        // attn[q][p]
    float* C = Cm + bz * (long)2048 * Lq;            // P[m][p]
    __shared__ __align__(16) float As[16][132];
    __shared__ __align__(16) float Bs[16][68];
    int tx = threadIdx.x;
    int m0 = blockIdx.x * 128, n0 = blockIdx.y * 64;
    int tr = tx >> 4, tc = tx & 15;
    int gr = tx & 127, qh = tx >> 7;          // A gather: row gr, q-half qh (8 q each)
    int gm = m0 + gr;
    int gc = gm >> 4, gu = (gm >> 2) & 3, gv = gm & 3;
    long cbase = ((long)bz * CN + gc) * 64;
    int bn4 = tx & 15, bkr = tx >> 4;
    float acc[8][4] = {};
    for (int k0 = 0; k0 < Lq; k0 += 16) {
        {
            int qbase = k0 + qh * 8;
            int qy = qbase >> 5;               // constant across the 8 (same 32-run)
            int y = 2 * qy + gu - 1;
            bool yok = ((unsigned)y < 64u);
#pragma unroll
            for (int j = 0; j < 8; ++j) {
                int q = qbase + j;
                int qx = q & 31;
                int x = 2 * qx + gv - 1;
                float val = 0.f;
                if (yok && (unsigned)x < 64u)
                    val = bsrc[(cbase + y) * 64 + x];
                As[qh * 8 + j][gr] = val;
            }
        }
        {
            float4 vb = *(const float4*)&B[(long)(k0 + bkr) * Lq + n0 + bn4 * 4];
            *(float4*)&Bs[bkr][bn4 * 4] = vb;
        }
        __syncthreads();
#pragma unroll
        for (int k = 0; k < 16; ++k) {
            float a_[8], b_[4];
            *(float4*)&a_[0] = *(const float4*)&As[k][tr * 8];
            *(float4*)&a_[4] = *(const float4*)&As[k][tr * 8 + 4];
            *(float4*)&b_[0] = *(const float4*)&Bs[k][tc * 4];
#pragma unroll
            for (int i = 0; i < 8; ++i)
#pragma unroll
                for (int j = 0; j < 4; ++j) acc[i][j] += a_[i] * b_[j];
        }
        __syncthreads();
    }
#pragma unroll
    for (int i = 0; i < 8; ++i) {
        int m = m0 + tr * 8 + i;
        *(float4*)&C[(long)m * Lq + n0 + tc * 4] =
            make_float4(acc[i][0], acc[i][1], acc[i][2], acc[i][3]);
    }
}

// ---------------- epilogue: fp32 tap-sum, /4, store FLOAT32 ----------------
__global__ __launch_bounds__(256) void k_epi2(const float* __restrict__ P, float* __restrict__ out) {
    int idx = blockIdx.x * 256 + threadIdx.x;   // 2*128*64*64 = 1048576
    int ox = idx & 63, oy = (idx >> 6) & 63, c = (idx >> 12) & 127, bb = idx >> 19;
    const float* Pb = P + (long)bb * 2048 * Lq;
    float s = 0.f;
#pragma unroll
    for (int u = 0; u < 4; ++u) {
        int t = oy + u - 2;
        if (t & 1) continue;                     // dilation hole
        int iy = t >> 1;
        if ((unsigned)iy >= (unsigned)HS) continue;
#pragma unroll
        for (int v = 0; v < 4; ++v) {
            int r = ox + v - 2;
            if (r & 1) continue;
            int ix = r >> 1;
            if ((unsigned)ix >= (unsigned)HS) continue;
            s += Pb[(long)((c << 4) + (3 - u) * 4 + (3 - v)) * Lq + (iy << 5) + ix];
        }
    }
    out[idx] = 0.25f * s;                        // FLOAT32 output
}

extern "C" void kernel_launch(void* const* d_in, const int* in_sizes, int n_in,
                              void* d_out, int out_size, void* d_ws, size_t ws_size,
                              hipStream_t stream) {
    const float* f    = (const float*)d_in[0];
    const float* bsrc = (const float*)d_in[1];
    const float* mask = (const float*)d_in[2];
    float* out = (float*)d_out;                  // fp32 output (reference returns fp32)
    float* ws = (float*)d_ws;

    // workspace layout (floats); total ~9.44M floats = 37.8 MB
    float* fdT   = ws;                       // 262144
    float* bdT   = fdT   + 262144;           // 262144
    float* normq = bdT   + 262144;           // 2048
    float* mmb   = normq + 2048;             // 1024
    float* AREA1 = mmb   + 1024;             // 2359296
    float* AREA2 = AREA1 + 2359296;          // 2359296
    float* C1    = AREA2 + 2359296;          // 2097152
    float* C2    = C1    + 2097152;          // 2097152
    float* wP   = AREA1;                     // becomes wn in place
    float* fpP  = AREA2;
    float* S0   = C1;
    float* S1   = C2;
    float* T    = AREA1;   // wP dead after GEMM
    float* T2   = AREA2;   // fpP dead after GEMM
    float* S2   = C1;      // S0 dead after fuse1
    float* attn = C2;      // S1 dead after first t4
    float* P    = AREA1;   // 4194304 floats spanning AREA1+AREA2; T,T2 dead

    hipLaunchKernelGGL(k_prep,       dim3(1024),      dim3(256),   0, stream, f, bsrc, fdT, bdT);
    hipLaunchKernelGGL(k_mm,         dim3(4),         dim3(256),   0, stream, mask, mmb);
    hipLaunchKernelGGL(k_patches,    dim3(9216),      dim3(256),   0, stream, fdT, bdT, fpP, wP);
    hipLaunchKernelGGL(k_rownorm,    dim3(2048),      dim3(64),    0, stream, wP, normq);
    hipLaunchKernelGGL(k_wn,         dim3(9216),      dim3(256),   0, stream, wP, normq);
    hipLaunchKernelGGL(k_gemm_nt64,  dim3(16, 16, 2), dim3(256),   0, stream, wP, fpP, S0, 1024, 1024, KP);
    hipLaunchKernelGGL(k_fuse_flat,  dim3(8192),      dim3(256),   0, stream, S0, S1);
    hipLaunchKernelGGL(k_t4,         dim3(8192),      dim3(256),   0, stream, S1, T);
    hipLaunchKernelGGL(k_fuse_flat,  dim3(8192),      dim3(256),   0, stream, T, T2);
    hipLaunchKernelGGL(k_t4,         dim3(8192),      dim3(256),   0, stream, T2, S2);
    hipLaunchKernelGGL(k_softmax,    dim3(16, 2),     dim3(64, 8), 0, stream, S2, mmb, attn);
    hipLaunchKernelGGL(k_gemm_gather,dim3(16, 16, 2), dim3(256),   0, stream, bsrc, attn, P);
    hipLaunchKernelGGL(k_epi2,       dim3(4096),      dim3(256),   0, stream, P, out);
}

// Round 12
// 217.222 us; speedup vs baseline: 1.8137x; 1.8137x over previous
//
#include <hip/hip_runtime.h>
#include <hip/hip_bf16.h>
#include <math.h>

constexpr int HS = 32;      // half spatial (32x32 grids)
constexpr int Lq = 1024;    // HS*HS
constexpr int CN = 128;     // channels
// batches = 2. Inputs fp32 (f, b, mask). Output fp32 (r11-verified).
// R12: Gram-trick scores (r2-verified bitwise == literal path), bf16-MFMA deconv GEMM,
// transposed row-softmax. Scores/softmax stay fp32 (argmax-critical); only the
// post-softmax GEMM uses bf16 operands (error ~0.03 << 0.0887 threshold).

typedef short bf16x8 __attribute__((ext_vector_type(8)));
typedef float f32x4  __attribute__((ext_vector_type(4)));

__device__ inline unsigned short f2bf(float x) {   // RNE float->bf16 bits
    union { float f; unsigned int u; } c; c.f = x;
    return (unsigned short)((c.u + 0x7FFF + ((c.u >> 16) & 1)) >> 16);
}

// ---------------- prep: downsample to 32x32, channel-last fp32 ----------------
__global__ __launch_bounds__(256) void k_prep(const float* __restrict__ f,
                                              const float* __restrict__ bsrc,
                                              float* __restrict__ fdT, float* __restrict__ bdT) {
    int idx = blockIdx.x * 256 + threadIdx.x;        // [0, 262144)
    int c  = idx & (CN - 1);
    int p  = (idx >> 7) & (Lq - 1);
    int bb = idx >> 17;
    int py = p >> 5, px = p & 31;
    long src = (((long)bb * CN + c) * 64 + 2 * py) * 64 + 2 * px;
    fdT[idx] = f[src];
    bdT[idx] = bsrc[src];
}

// ---------------- ssq[b*L+u] = sum_c bdT[u][c]^2 ----------------
__global__ __launch_bounds__(64) void k_ssq(const float* __restrict__ bdT, float* __restrict__ ssq) {
    int u = blockIdx.x;                  // 0..2047
    int tx = threadIdx.x;
    const float* row = bdT + (long)u * CN;
    float v0 = row[tx], v1 = row[tx + 64];
    float s = v0 * v0 + v1 * v1;
    for (int off = 32; off > 0; off >>= 1) s += __shfl_down(s, off, 64);
    if (tx == 0) ssq[u] = s;
}

// ---------------- norms[b*L+q] = sqrt(sum_{3x3 in-range} ssq + 0.1152) ----------------
__global__ __launch_bounds__(256) void k_norms(const float* __restrict__ ssq, float* __restrict__ norms) {
    int idx = blockIdx.x * 256 + threadIdx.x;   // 2048
    int q = idx & (Lq - 1);
    int bb = idx >> 10;
    int qy = q >> 5, qx = q & 31;
    float s = 0.1152f;
    for (int dk = -1; dk <= 1; ++dk) {
        int y = qy + dk; if ((unsigned)y >= (unsigned)HS) continue;
        for (int dl = -1; dl <= 1; ++dl) {
            int x = qx + dl; if ((unsigned)x >= (unsigned)HS) continue;
            s += ssq[bb * Lq + y * HS + x];
        }
    }
    norms[idx] = sqrtf(s);
}

// ---------------- mm[q] from mask batch 0 ----------------
__global__ __launch_bounds__(256) void k_mm(const float* __restrict__ mask, float* __restrict__ mmb) {
    int q = blockIdx.x * 256 + threadIdx.x;  // 1024
    int qy = q >> 5, qx = q & 31;
    float s = 0.f;
    for (int dk = -1; dk <= 1; ++dk) {
        int y = qy + dk; if ((unsigned)y >= (unsigned)HS) continue;
        for (int dl = -1; dl <= 1; ++dl) {
            int x = qx + dl; if ((unsigned)x >= (unsigned)HS) continue;
            s += mask[(8 * y) * 256 + 8 * x];
        }
    }
    mmb[q] = (s == 0.0f) ? 1.0f : 0.0f;
}

// ---------------- GEMM NT 64x64: G[u][v] = sum_c bdT[u][c]*fdT[v][c] (K=128) ----------------
__global__ __launch_bounds__(256) void k_gemm_nt64(const float* __restrict__ A, const float* __restrict__ B,
                                                   float* __restrict__ Cm, int Mdim, int Ndim, int Kdim) {
    const long bz = blockIdx.z;
    A  += bz * (long)Mdim * Kdim;
    B  += bz * (long)Ndim * Kdim;
    Cm += bz * (long)Mdim * Ndim;
    __shared__ __align__(16) float As[32][68];
    __shared__ __align__(16) float Bs[32][68];
    int tx = threadIdx.x;
    int m0 = blockIdx.x * 64, n0 = blockIdx.y * 64;
    int tr = tx >> 4, tc = tx & 15;
    int k4 = tx & 7, row = tx >> 3;
    float acc[4][4] = {};
    for (int k0 = 0; k0 < Kdim; k0 += 32) {
#pragma unroll
        for (int it = 0; it < 2; ++it) {
            int r = row + it * 32;
            float4 va = *(const float4*)&A[(long)(m0 + r) * Kdim + k0 + k4 * 4];
            As[k4 * 4 + 0][r] = va.x; As[k4 * 4 + 1][r] = va.y;
            As[k4 * 4 + 2][r] = va.z; As[k4 * 4 + 3][r] = va.w;
            float4 vb = *(const float4*)&B[(long)(n0 + r) * Kdim + k0 + k4 * 4];
            Bs[k4 * 4 + 0][r] = vb.x; Bs[k4 * 4 + 1][r] = vb.y;
            Bs[k4 * 4 + 2][r] = vb.z; Bs[k4 * 4 + 3][r] = vb.w;
        }
        __syncthreads();
#pragma unroll
        for (int k = 0; k < 32; ++k) {
            float4 a4 = *(const float4*)&As[k][tr * 4];
            float4 b4 = *(const float4*)&Bs[k][tc * 4];
            float a_[4] = {a4.x, a4.y, a4.z, a4.w};
            float b_[4] = {b4.x, b4.y, b4.z, b4.w};
#pragma unroll
            for (int i = 0; i < 4; ++i)
#pragma unroll
                for (int j = 0; j < 4; ++j) acc[i][j] += a_[i] * b_[j];
        }
        __syncthreads();
    }
#pragma unroll
    for (int i = 0; i < 4; ++i) {
        int m = m0 + tr * 4 + i;
        *(float4*)&Cm[(long)m * Ndim + n0 + tc * 4] =
            make_float4(acc[i][0], acc[i][1], acc[i][2], acc[i][3]);
    }
}

// ---------------- S0 from Gram: 9-shift band-sum / norms[q] (r2-verified) ----------------
__global__ __launch_bounds__(256) void k_s0(const float* __restrict__ G, const float* __restrict__ norms,
                                            float* __restrict__ S0) {
    int idx = blockIdx.x * 256 + threadIdx.x;  // 2*1024*1024
    int p  = idx & (Lq - 1);
    int q  = (idx >> 10) & (Lq - 1);
    int bb = idx >> 20;
    int qy = q >> 5, qx = q & 31, py = p >> 5, px = p & 31;
    const float* Gb = G + (long)bb * Lq * Lq;
    float s = 0.f;
#pragma unroll
    for (int dk = -1; dk <= 1; ++dk) {
        if ((unsigned)(qy + dk) >= (unsigned)HS || (unsigned)(py + dk) >= (unsigned)HS) continue;
#pragma unroll
        for (int dl = -1; dl <= 1; ++dl) {
            if ((unsigned)(qx + dl) >= (unsigned)HS || (unsigned)(px + dl) >= (unsigned)HS) continue;
            int sft = dk * HS + dl;
            s += Gb[(long)(q + sft) * Lq + (p + sft)];
        }
    }
    S0[idx] = s / norms[bb * Lq + q];
}

// ---------------- fuse pass 1: flat diagonal, wrap semantics (r2/r11-verified) ----------------
__global__ __launch_bounds__(256) void k_fuse1(const float* __restrict__ src, float* __restrict__ dst) {
    int idx = blockIdx.x * 256 + threadIdx.x;
    int j = idx & (Lq - 1);
    int i = (idx >> 10) & (Lq - 1);
    float s = src[idx];
    if (i > 0 && j > 0)               s += src[idx - (Lq + 1)];
    if (i < Lq - 1 && j < Lq - 1)     s += src[idx + (Lq + 1)];
    dst[idx] = s;
}

// ---------------- fuse pass 2: combined transposed-flatten diagonal (r2-verified) ----------------
__global__ __launch_bounds__(256) void k_fuse2(const float* __restrict__ S1, float* __restrict__ S2) {
    int idx = blockIdx.x * 256 + threadIdx.x;
    int p  = idx & (Lq - 1);
    int q  = (idx >> 10) & (Lq - 1);
    int bb = idx >> 20;
    int hb = q >> 5, wb = q & 31, hf = p >> 5, wf = p & 31;
    int ip = wb * HS + hb, jp = wf * HS + hf;
    const float* S = S1 + (long)bb * Lq * Lq;
    float s = 0.f;
#pragma unroll
    for (int d = -1; d <= 1; ++d) {
        int t = ip + d, r = jp + d;
        if ((unsigned)t < (unsigned)Lq && (unsigned)r < (unsigned)Lq) {
            int q2 = (t & 31) * HS + (t >> 5);
            int p2 = (r & 31) * HS + (r >> 5);
            s += S[(long)q2 * Lq + p2];
        }
    }
    S2[idx] = s;
}

// ---------------- tiled transpose: S2[q][p] -> S2T[p][q] ----------------
__global__ __launch_bounds__(256) void k_transp(const float* __restrict__ src, float* __restrict__ dst) {
    __shared__ float t[64][65];
    long base = (long)blockIdx.z << 20;
    int q0 = blockIdx.x * 64, p0 = blockIdx.y * 64;
    int tx = threadIdx.x & 63, ty = threadIdx.x >> 6;   // ty 0..3
#pragma unroll
    for (int i = 0; i < 16; ++i) {
        int r = ty * 16 + i;
        t[r][tx] = src[base + (long)(q0 + r) * Lq + p0 + tx];
    }
    __syncthreads();
#pragma unroll
    for (int i = 0; i < 16; ++i) {
        int r = ty * 16 + i;
        dst[base + (long)(p0 + r) * Lq + q0 + tx] = t[tx][r];
    }
}

// ---------------- row softmax over q on S2T[p][q]; writes attnT bf16 [p][q] ----------------
// one wave per (batch,p) row; denominator unmasked, numerator masked (r11-verified semantics)
__global__ __launch_bounds__(256) void k_softmaxT(const float* __restrict__ S2T, const float* __restrict__ mmb,
                                                  unsigned short* __restrict__ At) {
    int wid = blockIdx.x * 4 + (threadIdx.x >> 6);   // 0..2047
    int lane = threadIdx.x & 63;
    int bb = wid >> 10, p = wid & (Lq - 1);
    const float* row = S2T + ((long)bb << 20) + (long)p * Lq;
    unsigned short* orow = At + ((long)bb << 20) + (long)p * Lq;
    float x[16]; float mx = -1e30f;
#pragma unroll
    for (int i = 0; i < 16; ++i) {
        int q = i * 64 + lane;
        x[i] = row[q] * mmb[q] * 10.0f;
        mx = fmaxf(mx, x[i]);
    }
    for (int off = 32; off > 0; off >>= 1) mx = fmaxf(mx, __shfl_xor(mx, off, 64));
    float e[16]; float s = 0.f;
#pragma unroll
    for (int i = 0; i < 16; ++i) { e[i] = __expf(x[i] - mx); s += e[i]; }
    for (int off = 32; off > 0; off >>= 1) s += __shfl_xor(s, off, 64);
    float inv = 1.0f / s;
#pragma unroll
    for (int i = 0; i < 16; ++i) {
        int q = i * 64 + lane;
        orow[q] = f2bf(e[i] * mmb[q] * inv);
    }
}

// ---------------- Wm bf16: Wm[bz][m=(c,u,v)][q] = b[c, 2qy+u-1, 2qx+v-1] ----------------
__global__ __launch_bounds__(256) void k_wm(const float* __restrict__ bsrc, unsigned short* __restrict__ Wm) {
    int idx = blockIdx.x * 256 + threadIdx.x;   // 2*2048*1024
    int q  = idx & (Lq - 1);
    int m  = (idx >> 10) & 2047;
    int bb = idx >> 21;
    int c = m >> 4, u = (m >> 2) & 3, v = m & 3;
    int qy = q >> 5, qx = q & 31;
    int y = 2 * qy + u - 1, x = 2 * qx + v - 1;
    float val = 0.f;
    if ((unsigned)y < 64u && (unsigned)x < 64u)
        val = bsrc[(((long)bb * CN + c) * 64 + y) * 64 + x];
    Wm[idx] = f2bf(val);
}

// ---------------- MFMA GEMM: P[m][p] = sum_q Wm[m][q]*attnT[p][q], bf16 ops fp32 acc ----------------
// NT form, both operands K-contiguous bf16 -> direct 16B global->frag loads, no LDS.
// Fragment layouts (guide m89/m120-verified): A[m=lane&15][k=quad*8+j]; B[n=lane&15][k];
// D col=lane&15, row=quad*4+reg.
__global__ __launch_bounds__(256) void k_gemm_mfma(const unsigned short* __restrict__ WmA,
                                                   const unsigned short* __restrict__ At,
                                                   float* __restrict__ Cm) {
    const long bz = blockIdx.z;
    const unsigned short* A = WmA + bz * (2048L * Lq);
    const unsigned short* B = At  + bz * ((long)Lq * Lq);
    float* C = Cm + bz * (2048L * Lq);
    int w = threadIdx.x >> 6;            // wave 0..3
    int lane = threadIdx.x & 63;
    int quad = lane >> 4;
    int l16 = lane & 15;
    int m0 = blockIdx.x * 64 + w * 16;
    int n0 = blockIdx.y * 64;
    const unsigned short* aptr = A + (long)(m0 + l16) * Lq + quad * 8;
    const unsigned short* bptr = B + (long)(n0 + l16) * Lq + quad * 8;
    f32x4 acc0 = {0,0,0,0}, acc1 = {0,0,0,0}, acc2 = {0,0,0,0}, acc3 = {0,0,0,0};
    for (int k0 = 0; k0 < Lq; k0 += 32) {
        bf16x8 af = *(const bf16x8*)(aptr + k0);
        bf16x8 b0 = *(const bf16x8*)(bptr + k0);
        bf16x8 b1 = *(const bf16x8*)(bptr + 16 * Lq + k0);
        bf16x8 b2 = *(const bf16x8*)(bptr + 32 * Lq + k0);
        bf16x8 b3 = *(const bf16x8*)(bptr + 48 * Lq + k0);
        acc0 = __builtin_amdgcn_mfma_f32_16x16x32_bf16(af, b0, acc0, 0, 0, 0);
        acc1 = __builtin_amdgcn_mfma_f32_16x16x32_bf16(af, b1, acc1, 0, 0, 0);
        acc2 = __builtin_amdgcn_mfma_f32_16x16x32_bf16(af, b2, acc2, 0, 0, 0);
        acc3 = __builtin_amdgcn_mfma_f32_16x16x32_bf16(af, b3, acc3, 0, 0, 0);
    }
    int mrow = m0 + quad * 4;
#pragma unroll
    for (int r = 0; r < 4; ++r) {
        C[(long)(mrow + r) * Lq + n0 +  0 + l16] = acc0[r];
        C[(long)(mrow + r) * Lq + n0 + 16 + l16] = acc1[r];
        C[(long)(mrow + r) * Lq + n0 + 32 + l16] = acc2[r];
        C[(long)(mrow + r) * Lq + n0 + 48 + l16] = acc3[r];
    }
}

// ---------------- literal conv epilogue: fp32 tap-sum, /4, store fp32 (r11-verified) ----------------
__global__ __launch_bounds__(256) void k_epi2(const float* __restrict__ P, float* __restrict__ out) {
    int idx = blockIdx.x * 256 + threadIdx.x;   // 1048576
    int ox = idx & 63, oy = (idx >> 6) & 63, c = (idx >> 12) & 127, bb = idx >> 19;
    const float* Pb = P + (long)bb * 2048 * Lq;
    float s = 0.f;
#pragma unroll
    for (int u = 0; u < 4; ++u) {
        int t = oy + u - 2;
        if (t & 1) continue;
        int iy = t >> 1;
        if ((unsigned)iy >= (unsigned)HS) continue;
#pragma unroll
        for (int v = 0; v < 4; ++v) {
            int r = ox + v - 2;
            if (r & 1) continue;
            int ix = r >> 1;
            if ((unsigned)ix >= (unsigned)HS) continue;
            s += Pb[(long)((c << 4) + (3 - u) * 4 + (3 - v)) * Lq + (iy << 5) + ix];
        }
    }
    out[idx] = 0.25f * s;
}

extern "C" void kernel_launch(void* const* d_in, const int* in_sizes, int n_in,
                              void* d_out, int out_size, void* d_ws, size_t ws_size,
                              hipStream_t stream) {
    const float* f    = (const float*)d_in[0];
    const float* bsrc = (const float*)d_in[1];
    const float* mask = (const float*)d_in[2];
    float* out = (float*)d_out;
    float* ws = (float*)d_ws;

    // workspace (floats): 8,918,016 ≈ 35.7 MB
    float* fdT   = ws;                       // 262144
    float* bdT   = fdT   + 262144;           // 262144
    float* ssq   = bdT   + 262144;           // 2048
    float* norms = ssq   + 2048;             // 2048
    float* mmb   = norms + 2048;             // 1024
    float* AREA_G = mmb  + 1024;             // 2097152 : G -> attnT(bf16)
    float* C1    = AREA_G + 2097152;         // 2097152 : S0 -> S2 -> P[0:2M]
    float* C2    = C1    + 2097152;          // 2097152 : S1 -> S2T -> P[2M:4M]
    float* WmF   = C2    + 2097152;          // 2097152 : Wm bf16 (4M ushorts)
    float* G    = AREA_G;
    unsigned short* attnT = (unsigned short*)AREA_G;  // after G dead (post k_s0)
    float* S0   = C1;
    float* S1   = C2;
    float* S2   = C1;      // S0 dead after fuse1
    float* S2T  = C2;      // S1 dead after fuse2
    float* P    = C1;      // spans C1+C2 (4,194,304 floats); S2/S2T dead by then
    unsigned short* Wm = (unsigned short*)WmF;

    hipLaunchKernelGGL(k_prep,      dim3(1024),       dim3(256), 0, stream, f, bsrc, fdT, bdT);
    hipLaunchKernelGGL(k_ssq,       dim3(2048),       dim3(64),  0, stream, bdT, ssq);
    hipLaunchKernelGGL(k_norms,     dim3(8),          dim3(256), 0, stream, ssq, norms);
    hipLaunchKernelGGL(k_mm,        dim3(4),          dim3(256), 0, stream, mask, mmb);
    hipLaunchKernelGGL(k_gemm_nt64, dim3(16, 16, 2),  dim3(256), 0, stream, bdT, fdT, G, 1024, 1024, 128);
    hipLaunchKernelGGL(k_s0,        dim3(8192),       dim3(256), 0, stream, G, norms, S0);
    hipLaunchKernelGGL(k_fuse1,     dim3(8192),       dim3(256), 0, stream, S0, S1);
    hipLaunchKernelGGL(k_fuse2,     dim3(8192),       dim3(256), 0, stream, S1, S2);
    hipLaunchKernelGGL(k_transp,    dim3(16, 16, 2),  dim3(256), 0, stream, S2, S2T);
    hipLaunchKernelGGL(k_softmaxT,  dim3(512),        dim3(256), 0, stream, S2T, mmb, attnT);
    hipLaunchKernelGGL(k_wm,        dim3(16384),      dim3(256), 0, stream, bsrc, Wm);
    hipLaunchKernelGGL(k_gemm_mfma, dim3(32, 16, 2),  dim3(256), 0, stream, Wm, attnT, P);
    hipLaunchKernelGGL(k_epi2,      dim3(4096),       dim3(256), 0, stream, P, out);
}

// Round 13
// 177.063 us; speedup vs baseline: 2.2251x; 1.2268x over previous
//
#include <hip/hip_runtime.h>
#include <hip/hip_bf16.h>
#include <math.h>

constexpr int HS = 32;      // half spatial (32x32 grids)
constexpr int Lq = 1024;    // HS*HS
constexpr int CN = 128;     // channels
// batches = 2. Inputs fp32 (f, b, mask). Output fp32 (r11-verified).
// R13: LDS-tiled MFMA deconv GEMM (r12 frag math verified on HW; only frag source moves
// to LDS), fused fuse1+fuse2 stencil. Scores stay fp32 (argmax-critical).

typedef short bf16x8 __attribute__((ext_vector_type(8)));
typedef float f32x4  __attribute__((ext_vector_type(4)));

__device__ inline unsigned short f2bf(float x) {   // RNE float->bf16 bits
    union { float f; unsigned int u; } c; c.f = x;
    return (unsigned short)((c.u + 0x7FFF + ((c.u >> 16) & 1)) >> 16);
}

// ---------------- prep: downsample to 32x32, channel-last fp32 ----------------
__global__ __launch_bounds__(256) void k_prep(const float* __restrict__ f,
                                              const float* __restrict__ bsrc,
                                              float* __restrict__ fdT, float* __restrict__ bdT) {
    int idx = blockIdx.x * 256 + threadIdx.x;        // [0, 262144)
    int c  = idx & (CN - 1);
    int p  = (idx >> 7) & (Lq - 1);
    int bb = idx >> 17;
    int py = p >> 5, px = p & 31;
    long src = (((long)bb * CN + c) * 64 + 2 * py) * 64 + 2 * px;
    fdT[idx] = f[src];
    bdT[idx] = bsrc[src];
}

// ---------------- ssq[b*L+u] = sum_c bdT[u][c]^2 ----------------
__global__ __launch_bounds__(64) void k_ssq(const float* __restrict__ bdT, float* __restrict__ ssq) {
    int u = blockIdx.x;                  // 0..2047
    int tx = threadIdx.x;
    const float* row = bdT + (long)u * CN;
    float v0 = row[tx], v1 = row[tx + 64];
    float s = v0 * v0 + v1 * v1;
    for (int off = 32; off > 0; off >>= 1) s += __shfl_down(s, off, 64);
    if (tx == 0) ssq[u] = s;
}

// ---------------- norms[b*L+q] = sqrt(sum_{3x3 in-range} ssq + 0.1152) ----------------
__global__ __launch_bounds__(256) void k_norms(const float* __restrict__ ssq, float* __restrict__ norms) {
    int idx = blockIdx.x * 256 + threadIdx.x;   // 2048
    int q = idx & (Lq - 1);
    int bb = idx >> 10;
    int qy = q >> 5, qx = q & 31;
    float s = 0.1152f;
    for (int dk = -1; dk <= 1; ++dk) {
        int y = qy + dk; if ((unsigned)y >= (unsigned)HS) continue;
        for (int dl = -1; dl <= 1; ++dl) {
            int x = qx + dl; if ((unsigned)x >= (unsigned)HS) continue;
            s += ssq[bb * Lq + y * HS + x];
        }
    }
    norms[idx] = sqrtf(s);
}

// ---------------- mm[q] from mask batch 0 ----------------
__global__ __launch_bounds__(256) void k_mm(const float* __restrict__ mask, float* __restrict__ mmb) {
    int q = blockIdx.x * 256 + threadIdx.x;  // 1024
    int qy = q >> 5, qx = q & 31;
    float s = 0.f;
    for (int dk = -1; dk <= 1; ++dk) {
        int y = qy + dk; if ((unsigned)y >= (unsigned)HS) continue;
        for (int dl = -1; dl <= 1; ++dl) {
            int x = qx + dl; if ((unsigned)x >= (unsigned)HS) continue;
            s += mask[(8 * y) * 256 + 8 * x];
        }
    }
    mmb[q] = (s == 0.0f) ? 1.0f : 0.0f;
}

// ---------------- GEMM NT 64x64: G[u][v] = sum_c bdT[u][c]*fdT[v][c] (K=128, fp32) ----------------
__global__ __launch_bounds__(256) void k_gemm_nt64(const float* __restrict__ A, const float* __restrict__ B,
                                                   float* __restrict__ Cm, int Mdim, int Ndim, int Kdim) {
    const long bz = blockIdx.z;
    A  += bz * (long)Mdim * Kdim;
    B  += bz * (long)Ndim * Kdim;
    Cm += bz * (long)Mdim * Ndim;
    __shared__ __align__(16) float As[32][68];
    __shared__ __align__(16) float Bs[32][68];
    int tx = threadIdx.x;
    int m0 = blockIdx.x * 64, n0 = blockIdx.y * 64;
    int tr = tx >> 4, tc = tx & 15;
    int k4 = tx & 7, row = tx >> 3;
    float acc[4][4] = {};
    for (int k0 = 0; k0 < Kdim; k0 += 32) {
#pragma unroll
        for (int it = 0; it < 2; ++it) {
            int r = row + it * 32;
            float4 va = *(const float4*)&A[(long)(m0 + r) * Kdim + k0 + k4 * 4];
            As[k4 * 4 + 0][r] = va.x; As[k4 * 4 + 1][r] = va.y;
            As[k4 * 4 + 2][r] = va.z; As[k4 * 4 + 3][r] = va.w;
            float4 vb = *(const float4*)&B[(long)(n0 + r) * Kdim + k0 + k4 * 4];
            Bs[k4 * 4 + 0][r] = vb.x; Bs[k4 * 4 + 1][r] = vb.y;
            Bs[k4 * 4 + 2][r] = vb.z; Bs[k4 * 4 + 3][r] = vb.w;
        }
        __syncthreads();
#pragma unroll
        for (int k = 0; k < 32; ++k) {
            float4 a4 = *(const float4*)&As[k][tr * 4];
            float4 b4 = *(const float4*)&Bs[k][tc * 4];
            float a_[4] = {a4.x, a4.y, a4.z, a4.w};
            float b_[4] = {b4.x, b4.y, b4.z, b4.w};
#pragma unroll
            for (int i = 0; i < 4; ++i)
#pragma unroll
                for (int j = 0; j < 4; ++j) acc[i][j] += a_[i] * b_[j];
        }
        __syncthreads();
    }
#pragma unroll
    for (int i = 0; i < 4; ++i) {
        int m = m0 + tr * 4 + i;
        *(float4*)&Cm[(long)m * Ndim + n0 + tc * 4] =
            make_float4(acc[i][0], acc[i][1], acc[i][2], acc[i][3]);
    }
}

// ---------------- S0 from Gram: 9-shift band-sum / norms[q] (r2/r12-verified) ----------------
__global__ __launch_bounds__(256) void k_s0(const float* __restrict__ G, const float* __restrict__ norms,
                                            float* __restrict__ S0) {
    int idx = blockIdx.x * 256 + threadIdx.x;  // 2*1024*1024
    int p  = idx & (Lq - 1);
    int q  = (idx >> 10) & (Lq - 1);
    int bb = idx >> 20;
    int qy = q >> 5, qx = q & 31, py = p >> 5, px = p & 31;
    const float* Gb = G + (long)bb * Lq * Lq;
    float s = 0.f;
#pragma unroll
    for (int dk = -1; dk <= 1; ++dk) {
        if ((unsigned)(qy + dk) >= (unsigned)HS || (unsigned)(py + dk) >= (unsigned)HS) continue;
#pragma unroll
        for (int dl = -1; dl <= 1; ++dl) {
            if ((unsigned)(qx + dl) >= (unsigned)HS || (unsigned)(px + dl) >= (unsigned)HS) continue;
            int sft = dk * HS + dl;
            s += Gb[(long)(q + sft) * Lq + (p + sft)];
        }
    }
    S0[idx] = s / norms[bb * Lq + q];
}

// ---------------- FUSED fuse1+fuse2: S2 = F2(F1(S0)), 9-point gather, wrap semantics ----------------
// F1: flat-diag +/-1025 with flat bounds; F2: transposed-flat diag with its own bounds.
__global__ __launch_bounds__(256) void k_fuse12(const float* __restrict__ S0, float* __restrict__ S2) {
    int idx = blockIdx.x * 256 + threadIdx.x;   // 2*1024*1024
    int p  = idx & (Lq - 1);
    int q  = (idx >> 10) & (Lq - 1);
    int bb = idx >> 20;
    int hb = q >> 5, wb = q & 31, hf = p >> 5, wf = p & 31;
    int ip = wb * HS + hb, jp = wf * HS + hf;
    const float* S = S0 + (long)bb * Lq * Lq;
    float s = 0.f;
#pragma unroll
    for (int d = -1; d <= 1; ++d) {
        int t = ip + d, r = jp + d;
        if ((unsigned)t < (unsigned)Lq && (unsigned)r < (unsigned)Lq) {
            int q2 = (t & 31) * HS + (t >> 5);
            int p2 = (r & 31) * HS + (r >> 5);
            long base = (long)q2 * Lq + p2;
            float v = S[base];
            if (q2 > 0 && p2 > 0)             v += S[base - (Lq + 1)];
            if (q2 < Lq - 1 && p2 < Lq - 1)   v += S[base + (Lq + 1)];
            s += v;
        }
    }
    S2[idx] = s;
}

// ---------------- tiled transpose: S2[q][p] -> S2T[p][q] ----------------
__global__ __launch_bounds__(256) void k_transp(const float* __restrict__ src, float* __restrict__ dst) {
    __shared__ float t[64][65];
    long base = (long)blockIdx.z << 20;
    int q0 = blockIdx.x * 64, p0 = blockIdx.y * 64;
    int tx = threadIdx.x & 63, ty = threadIdx.x >> 6;   // ty 0..3
#pragma unroll
    for (int i = 0; i < 16; ++i) {
        int r = ty * 16 + i;
        t[r][tx] = src[base + (long)(q0 + r) * Lq + p0 + tx];
    }
    __syncthreads();
#pragma unroll
    for (int i = 0; i < 16; ++i) {
        int r = ty * 16 + i;
        dst[base + (long)(p0 + r) * Lq + q0 + tx] = t[tx][r];
    }
}

// ---------------- row softmax over q on S2T[p][q]; writes attnT bf16 [p][q] ----------------
__global__ __launch_bounds__(256) void k_softmaxT(const float* __restrict__ S2T, const float* __restrict__ mmb,
                                                  unsigned short* __restrict__ At) {
    int wid = blockIdx.x * 4 + (threadIdx.x >> 6);   // 0..2047
    int lane = threadIdx.x & 63;
    int bb = wid >> 10, p = wid & (Lq - 1);
    const float* row = S2T + ((long)bb << 20) + (long)p * Lq;
    unsigned short* orow = At + ((long)bb << 20) + (long)p * Lq;
    float x[16]; float mx = -1e30f;
#pragma unroll
    for (int i = 0; i < 16; ++i) {
        int q = i * 64 + lane;
        x[i] = row[q] * mmb[q] * 10.0f;
        mx = fmaxf(mx, x[i]);
    }
    for (int off = 32; off > 0; off >>= 1) mx = fmaxf(mx, __shfl_xor(mx, off, 64));
    float e[16]; float s = 0.f;
#pragma unroll
    for (int i = 0; i < 16; ++i) { e[i] = __expf(x[i] - mx); s += e[i]; }
    for (int off = 32; off > 0; off >>= 1) s += __shfl_xor(s, off, 64);
    float inv = 1.0f / s;
#pragma unroll
    for (int i = 0; i < 16; ++i) {
        int q = i * 64 + lane;
        orow[q] = f2bf(e[i] * mmb[q] * inv);
    }
}

// ---------------- Wm bf16: Wm[bz][m=(c,u,v)][q] = b[c, 2qy+u-1, 2qx+v-1] ----------------
__global__ __launch_bounds__(256) void k_wm(const float* __restrict__ bsrc, unsigned short* __restrict__ Wm) {
    int idx = blockIdx.x * 256 + threadIdx.x;   // 2*2048*1024
    int q  = idx & (Lq - 1);
    int m  = (idx >> 10) & 2047;
    int bb = idx >> 21;
    int c = m >> 4, u = (m >> 2) & 3, v = m & 3;
    int qy = q >> 5, qx = q & 31;
    int y = 2 * qy + u - 1, x = 2 * qx + v - 1;
    float val = 0.f;
    if ((unsigned)y < 64u && (unsigned)x < 64u)
        val = bsrc[(((long)bb * CN + c) * 64 + y) * 64 + x];
    Wm[idx] = f2bf(val);
}

// ---------------- LDS-tiled MFMA GEMM: P[m][p] = sum_q Wm[m][q]*attnT[p][q] ----------------
// 64x64 tile/block, 4 waves (wave w owns m rows w*16..w*16+15). K-step 32.
// LDS layout (shorts): slab(r>>4)*512 + kq*128 + (r&15)*8  -> frag reads are 16-lane-
// consecutive b128s. Fragment math identical to r12 (HW-verified):
// A[m=l16][k=quad*8+j], B[n=l16][k], D col=l16 row=quad*4+reg.
__global__ __launch_bounds__(256) void k_gemm_mfma(const unsigned short* __restrict__ WmA,
                                                   const unsigned short* __restrict__ At,
                                                   float* __restrict__ Cm) {
    const long bz = blockIdx.z;
    const unsigned short* A = WmA + bz * (2048L * Lq);
    const unsigned short* B = At  + bz * ((long)Lq * Lq);
    float* C = Cm + bz * (2048L * Lq);
    __shared__ __align__(16) unsigned short As[2048];
    __shared__ __align__(16) unsigned short Bs[2048];
    int t = threadIdx.x;
    int w = t >> 6, lane = t & 63;
    int quad = lane >> 4, l16 = lane & 15;
    int m0 = blockIdx.x * 64, n0 = blockIdx.y * 64;
    // staging: thread stages row (w*16+l16), k-quad = quad, for both A and B
    const unsigned short* aS = A + (long)(m0 + w * 16 + l16) * Lq + quad * 8;
    const unsigned short* bS = B + (long)(n0 + w * 16 + l16) * Lq + quad * 8;
    int sidx = w * 512 + quad * 128 + l16 * 8;
    int fidx = quad * 128 + l16 * 8;
    f32x4 acc0 = {0,0,0,0}, acc1 = {0,0,0,0}, acc2 = {0,0,0,0}, acc3 = {0,0,0,0};
    for (int k0 = 0; k0 < Lq; k0 += 32) {
        bf16x8 av = *(const bf16x8*)(aS + k0);      // issued before barrier: overlaps
        bf16x8 bv = *(const bf16x8*)(bS + k0);      // prior iteration's MFMAs
        __syncthreads();                             // LDS safe to overwrite
        *(bf16x8*)&As[sidx] = av;
        *(bf16x8*)&Bs[sidx] = bv;
        __syncthreads();                             // LDS ready
        bf16x8 af = *(const bf16x8*)&As[w * 512 + fidx];
        bf16x8 b0 = *(const bf16x8*)&Bs[fidx];
        bf16x8 b1 = *(const bf16x8*)&Bs[512 + fidx];
        bf16x8 b2 = *(const bf16x8*)&Bs[1024 + fidx];
        bf16x8 b3 = *(const bf16x8*)&Bs[1536 + fidx];
        acc0 = __builtin_amdgcn_mfma_f32_16x16x32_bf16(af, b0, acc0, 0, 0, 0);
        acc1 = __builtin_amdgcn_mfma_f32_16x16x32_bf16(af, b1, acc1, 0, 0, 0);
        acc2 = __builtin_amdgcn_mfma_f32_16x16x32_bf16(af, b2, acc2, 0, 0, 0);
        acc3 = __builtin_amdgcn_mfma_f32_16x16x32_bf16(af, b3, acc3, 0, 0, 0);
    }
    int mrow = m0 + w * 16 + quad * 4;
#pragma unroll
    for (int r = 0; r < 4; ++r) {
        C[(long)(mrow + r) * Lq + n0 +  0 + l16] = acc0[r];
        C[(long)(mrow + r) * Lq + n0 + 16 + l16] = acc1[r];
        C[(long)(mrow + r) * Lq + n0 + 32 + l16] = acc2[r];
        C[(long)(mrow + r) * Lq + n0 + 48 + l16] = acc3[r];
    }
}

// ---------------- literal conv epilogue: fp32 tap-sum, /4, store fp32 (r11-verified) ----------------
__global__ __launch_bounds__(256) void k_epi2(const float* __restrict__ P, float* __restrict__ out) {
    int idx = blockIdx.x * 256 + threadIdx.x;   // 1048576
    int ox = idx & 63, oy = (idx >> 6) & 63, c = (idx >> 12) & 127, bb = idx >> 19;
    const float* Pb = P + (long)bb * 2048 * Lq;
    float s = 0.f;
#pragma unroll
    for (int u = 0; u < 4; ++u) {
        int t = oy + u - 2;
        if (t & 1) continue;
        int iy = t >> 1;
        if ((unsigned)iy >= (unsigned)HS) continue;
#pragma unroll
        for (int v = 0; v < 4; ++v) {
            int r = ox + v - 2;
            if (r & 1) continue;
            int ix = r >> 1;
            if ((unsigned)ix >= (unsigned)HS) continue;
            s += Pb[(long)((c << 4) + (3 - u) * 4 + (3 - v)) * Lq + (iy << 5) + ix];
        }
    }
    out[idx] = 0.25f * s;
}

extern "C" void kernel_launch(void* const* d_in, const int* in_sizes, int n_in,
                              void* d_out, int out_size, void* d_ws, size_t ws_size,
                              hipStream_t stream) {
    const float* f    = (const float*)d_in[0];
    const float* bsrc = (const float*)d_in[1];
    const float* mask = (const float*)d_in[2];
    float* out = (float*)d_out;
    float* ws = (float*)d_ws;

    // workspace (floats): ~35.7 MB
    float* fdT   = ws;                       // 262144
    float* bdT   = fdT   + 262144;           // 262144
    float* ssq   = bdT   + 262144;           // 2048
    float* norms = ssq   + 2048;             // 2048
    float* mmb   = norms + 2048;             // 1024
    float* AREA_G = mmb  + 1024;             // 2097152 : G -> attnT(bf16)
    float* C1    = AREA_G + 2097152;         // 2097152 : S0 -> S2T -> P[0:2M]
    float* C2    = C1    + 2097152;          // 2097152 : S2 -> P[2M:4M]
    float* WmF   = C2    + 2097152;          // 2097152 : Wm bf16 (4M ushorts)
    float* G    = AREA_G;
    unsigned short* attnT = (unsigned short*)AREA_G;  // G dead after k_s0
    float* S0   = C1;
    float* S2   = C2;      // fuse12: C1 -> C2
    float* S2T  = C1;      // transp: C2 -> C1 (S0 dead)
    float* P    = C1;      // spans C1+C2 (4,194,304 floats); S2T/S2 dead after softmax
    unsigned short* Wm = (unsigned short*)WmF;

    hipLaunchKernelGGL(k_prep,      dim3(1024),       dim3(256), 0, stream, f, bsrc, fdT, bdT);
    hipLaunchKernelGGL(k_ssq,       dim3(2048),       dim3(64),  0, stream, bdT, ssq);
    hipLaunchKernelGGL(k_norms,     dim3(8),          dim3(256), 0, stream, ssq, norms);
    hipLaunchKernelGGL(k_mm,        dim3(4),          dim3(256), 0, stream, mask, mmb);
    hipLaunchKernelGGL(k_gemm_nt64, dim3(16, 16, 2),  dim3(256), 0, stream, bdT, fdT, G, 1024, 1024, 128);
    hipLaunchKernelGGL(k_s0,        dim3(8192),       dim3(256), 0, stream, G, norms, S0);
    hipLaunchKernelGGL(k_fuse12,    dim3(8192),       dim3(256), 0, stream, S0, S2);
    hipLaunchKernelGGL(k_transp,    dim3(16, 16, 2),  dim3(256), 0, stream, S2, S2T);
    hipLaunchKernelGGL(k_softmaxT,  dim3(512),        dim3(256), 0, stream, S2T, mmb, attnT);
    hipLaunchKernelGGL(k_wm,        dim3(16384),      dim3(256), 0, stream, bsrc, Wm);
    hipLaunchKernelGGL(k_gemm_mfma, dim3(32, 16, 2),  dim3(256), 0, stream, Wm, attnT, P);
    hipLaunchKernelGGL(k_epi2,      dim3(4096),       dim3(256), 0, stream, P, out);
}

// Round 14
// 165.274 us; speedup vs baseline: 2.3838x; 1.0713x over previous
//
#include <hip/hip_runtime.h>
#include <hip/hip_bf16.h>
#include <math.h>

constexpr int HS = 32;      // half spatial (32x32 grids)
constexpr int Lq = 1024;    // HS*HS
constexpr int CN = 128;     // channels
// batches = 2. Inputs fp32 (f, b, mask). Output fp32 (r11-verified).
// R14: Gram GEMM -> MFMA bf16x2 error-compensated (err ~2^-16, emits G^T);
// transposed score pipeline (s0/fuse12 are (q,p)-swap symmetric -> run on T layout,
// k_transp eliminated). Deconv MFMA GEMM + softmax + epilogue unchanged (r13-verified).

typedef short bf16x8 __attribute__((ext_vector_type(8)));
typedef float f32x4  __attribute__((ext_vector_type(4)));

__device__ inline unsigned short f2bf(float x) {   // RNE float->bf16 bits
    union { float f; unsigned int u; } c; c.f = x;
    return (unsigned short)((c.u + 0x7FFF + ((c.u >> 16) & 1)) >> 16);
}
__device__ inline float bf2f(unsigned short h) {
    union { unsigned int u; float f; } c; c.u = ((unsigned int)h) << 16;
    return c.f;
}

// ---------------- prep: downsample; bdT fp32 (for ssq) + hi/lo bf16 splits for Gram ----------------
__global__ __launch_bounds__(256) void k_prep(const float* __restrict__ f,
                                              const float* __restrict__ bsrc,
                                              float* __restrict__ bdT,
                                              unsigned short* __restrict__ fH, unsigned short* __restrict__ fL,
                                              unsigned short* __restrict__ bH, unsigned short* __restrict__ bL) {
    int idx = blockIdx.x * 256 + threadIdx.x;        // [0, 262144)
    int c  = idx & (CN - 1);
    int p  = (idx >> 7) & (Lq - 1);
    int bb = idx >> 17;
    int py = p >> 5, px = p & 31;
    long src = (((long)bb * CN + c) * 64 + 2 * py) * 64 + 2 * px;
    float fv = f[src], bv = bsrc[src];
    bdT[idx] = bv;
    unsigned short fh = f2bf(fv);
    unsigned short bh = f2bf(bv);
    fH[idx] = fh; fL[idx] = f2bf(fv - bf2f(fh));
    bH[idx] = bh; bL[idx] = f2bf(bv - bf2f(bh));
}

// ---------------- ssq[b*L+u] = sum_c bdT[u][c]^2 ----------------
__global__ __launch_bounds__(64) void k_ssq(const float* __restrict__ bdT, float* __restrict__ ssq) {
    int u = blockIdx.x;                  // 0..2047
    int tx = threadIdx.x;
    const float* row = bdT + (long)u * CN;
    float v0 = row[tx], v1 = row[tx + 64];
    float s = v0 * v0 + v1 * v1;
    for (int off = 32; off > 0; off >>= 1) s += __shfl_down(s, off, 64);
    if (tx == 0) ssq[u] = s;
}

// ---------------- norms[b*L+q] = sqrt(sum_{3x3 in-range} ssq + 0.1152) ----------------
__global__ __launch_bounds__(256) void k_norms(const float* __restrict__ ssq, float* __restrict__ norms) {
    int idx = blockIdx.x * 256 + threadIdx.x;   // 2048
    int q = idx & (Lq - 1);
    int bb = idx >> 10;
    int qy = q >> 5, qx = q & 31;
    float s = 0.1152f;
    for (int dk = -1; dk <= 1; ++dk) {
        int y = qy + dk; if ((unsigned)y >= (unsigned)HS) continue;
        for (int dl = -1; dl <= 1; ++dl) {
            int x = qx + dl; if ((unsigned)x >= (unsigned)HS) continue;
            s += ssq[bb * Lq + y * HS + x];
        }
    }
    norms[idx] = sqrtf(s);
}

// ---------------- mm[q] from mask batch 0 ----------------
__global__ __launch_bounds__(256) void k_mm(const float* __restrict__ mask, float* __restrict__ mmb) {
    int q = blockIdx.x * 256 + threadIdx.x;  // 1024
    int qy = q >> 5, qx = q & 31;
    float s = 0.f;
    for (int dk = -1; dk <= 1; ++dk) {
        int y = qy + dk; if ((unsigned)y >= (unsigned)HS) continue;
        for (int dl = -1; dl <= 1; ++dl) {
            int x = qx + dl; if ((unsigned)x >= (unsigned)HS) continue;
            s += mask[(8 * y) * 256 + 8 * x];
        }
    }
    mmb[q] = (s == 0.0f) ? 1.0f : 0.0f;
}

// ---------------- Gram MFMA bf16x2: GT[p'][q'] = sum_c fd[p'][c]*bd[q'][c] ----------------
// A = fd (m rows = p'), B = bd (n rows = q'); 3-product compensation Ah*Bh+Ah*Bl+Al*Bh.
// Block = 4 waves, 64x64 tile; wave = 32x32 (2x2 of 16x16). K=128 unrolled.
// Frag layout (r12/r13 HW-verified): A[m=l16][k=quad*8+j], B[n=l16][k], D col=l16 row=quad*4+r.
__global__ __launch_bounds__(256) void k_gram(const unsigned short* __restrict__ fH,
                                              const unsigned short* __restrict__ fL,
                                              const unsigned short* __restrict__ bH,
                                              const unsigned short* __restrict__ bL,
                                              float* __restrict__ GT) {
    const long bz = blockIdx.z;
    const unsigned short* AH = fH + bz * 131072;
    const unsigned short* AL = fL + bz * 131072;
    const unsigned short* BH = bH + bz * 131072;
    const unsigned short* BL = bL + bz * 131072;
    float* C = GT + (bz << 20);
    int t = threadIdx.x, w = t >> 6, lane = t & 63, quad = lane >> 4, l16 = lane & 15;
    int wm = blockIdx.x * 64 + (w & 1) * 32;
    int wn = blockIdx.y * 64 + (w >> 1) * 32;
    int ko = quad * 8;
    f32x4 acc[2][2] = {};
#pragma unroll
    for (int k0 = 0; k0 < 128; k0 += 32) {
        bf16x8 ah0 = *(const bf16x8*)&AH[(wm + l16) * 128 + ko + k0];
        bf16x8 ah1 = *(const bf16x8*)&AH[(wm + 16 + l16) * 128 + ko + k0];
        bf16x8 al0 = *(const bf16x8*)&AL[(wm + l16) * 128 + ko + k0];
        bf16x8 al1 = *(const bf16x8*)&AL[(wm + 16 + l16) * 128 + ko + k0];
        bf16x8 bh0 = *(const bf16x8*)&BH[(wn + l16) * 128 + ko + k0];
        bf16x8 bh1 = *(const bf16x8*)&BH[(wn + 16 + l16) * 128 + ko + k0];
        bf16x8 bl0 = *(const bf16x8*)&BL[(wn + l16) * 128 + ko + k0];
        bf16x8 bl1 = *(const bf16x8*)&BL[(wn + 16 + l16) * 128 + ko + k0];
        acc[0][0] = __builtin_amdgcn_mfma_f32_16x16x32_bf16(ah0, bh0, acc[0][0], 0, 0, 0);
        acc[0][1] = __builtin_amdgcn_mfma_f32_16x16x32_bf16(ah0, bh1, acc[0][1], 0, 0, 0);
        acc[1][0] = __builtin_amdgcn_mfma_f32_16x16x32_bf16(ah1, bh0, acc[1][0], 0, 0, 0);
        acc[1][1] = __builtin_amdgcn_mfma_f32_16x16x32_bf16(ah1, bh1, acc[1][1], 0, 0, 0);
        acc[0][0] = __builtin_amdgcn_mfma_f32_16x16x32_bf16(ah0, bl0, acc[0][0], 0, 0, 0);
        acc[0][1] = __builtin_amdgcn_mfma_f32_16x16x32_bf16(ah0, bl1, acc[0][1], 0, 0, 0);
        acc[1][0] = __builtin_amdgcn_mfma_f32_16x16x32_bf16(ah1, bl0, acc[1][0], 0, 0, 0);
        acc[1][1] = __builtin_amdgcn_mfma_f32_16x16x32_bf16(ah1, bl1, acc[1][1], 0, 0, 0);
        acc[0][0] = __builtin_amdgcn_mfma_f32_16x16x32_bf16(al0, bh0, acc[0][0], 0, 0, 0);
        acc[0][1] = __builtin_amdgcn_mfma_f32_16x16x32_bf16(al0, bh1, acc[0][1], 0, 0, 0);
        acc[1][0] = __builtin_amdgcn_mfma_f32_16x16x32_bf16(al1, bh0, acc[1][0], 0, 0, 0);
        acc[1][1] = __builtin_amdgcn_mfma_f32_16x16x32_bf16(al1, bh1, acc[1][1], 0, 0, 0);
    }
#pragma unroll
    for (int i = 0; i < 2; ++i)
#pragma unroll
        for (int j = 0; j < 2; ++j) {
            int mrow = wm + i * 16 + quad * 4;
            int ncol = wn + j * 16 + l16;
#pragma unroll
            for (int r = 0; r < 4; ++r)
                C[(long)(mrow + r) * Lq + ncol] = acc[i][j][r];
        }
}

// ---------------- S0T[p][q] = band9(GT) / norms[q]  (T-layout; coalesced over q) ----------------
__global__ __launch_bounds__(256) void k_s0T(const float* __restrict__ GT, const float* __restrict__ norms,
                                             float* __restrict__ S0T) {
    int idx = blockIdx.x * 256 + threadIdx.x;  // 2*1024*1024
    int q  = idx & (Lq - 1);
    int pp = (idx >> 10) & (Lq - 1);
    int bb = idx >> 20;
    int qy = q >> 5, qx = q & 31, py = pp >> 5, px = pp & 31;
    const float* Gb = GT + ((long)bb << 20);
    float s = 0.f;
#pragma unroll
    for (int dk = -1; dk <= 1; ++dk) {
        if ((unsigned)(qy + dk) >= (unsigned)HS || (unsigned)(py + dk) >= (unsigned)HS) continue;
#pragma unroll
        for (int dl = -1; dl <= 1; ++dl) {
            if ((unsigned)(qx + dl) >= (unsigned)HS || (unsigned)(px + dl) >= (unsigned)HS) continue;
            int sft = dk * HS + dl;
            s += Gb[(long)(pp + sft) * Lq + (q + sft)];
        }
    }
    S0T[idx] = s / norms[bb * Lq + q];
}

// ---------------- FUSED fuse1+fuse2 (symmetric under (q,p) swap -> valid on T layout) ----------------
// input S0T, output S2T. Index code identical to r13 (HW-verified in normal space).
__global__ __launch_bounds__(256) void k_fuse12(const float* __restrict__ S0, float* __restrict__ S2) {
    int idx = blockIdx.x * 256 + threadIdx.x;   // 2*1024*1024
    int p  = idx & (Lq - 1);
    int q  = (idx >> 10) & (Lq - 1);
    int bb = idx >> 20;
    int hb = q >> 5, wb = q & 31, hf = p >> 5, wf = p & 31;
    int ip = wb * HS + hb, jp = wf * HS + hf;
    const float* S = S0 + (long)bb * Lq * Lq;
    float s = 0.f;
#pragma unroll
    for (int d = -1; d <= 1; ++d) {
        int t = ip + d, r = jp + d;
        if ((unsigned)t < (unsigned)Lq && (unsigned)r < (unsigned)Lq) {
            int q2 = (t & 31) * HS + (t >> 5);
            int p2 = (r & 31) * HS + (r >> 5);
            long base = (long)q2 * Lq + p2;
            float v = S[base];
            if (q2 > 0 && p2 > 0)             v += S[base - (Lq + 1)];
            if (q2 < Lq - 1 && p2 < Lq - 1)   v += S[base + (Lq + 1)];
            s += v;
        }
    }
    S2[idx] = s;
}

// ---------------- row softmax over q on S2T[p][q]; writes attnT bf16 [p][q] ----------------
__global__ __launch_bounds__(256) void k_softmaxT(const float* __restrict__ S2T, const float* __restrict__ mmb,
                                                  unsigned short* __restrict__ At) {
    int wid = blockIdx.x * 4 + (threadIdx.x >> 6);   // 0..2047
    int lane = threadIdx.x & 63;
    int bb = wid >> 10, p = wid & (Lq - 1);
    const float* row = S2T + ((long)bb << 20) + (long)p * Lq;
    unsigned short* orow = At + ((long)bb << 20) + (long)p * Lq;
    float x[16]; float mx = -1e30f;
#pragma unroll
    for (int i = 0; i < 16; ++i) {
        int q = i * 64 + lane;
        x[i] = row[q] * mmb[q] * 10.0f;
        mx = fmaxf(mx, x[i]);
    }
    for (int off = 32; off > 0; off >>= 1) mx = fmaxf(mx, __shfl_xor(mx, off, 64));
    float e[16]; float s = 0.f;
#pragma unroll
    for (int i = 0; i < 16; ++i) { e[i] = __expf(x[i] - mx); s += e[i]; }
    for (int off = 32; off > 0; off >>= 1) s += __shfl_xor(s, off, 64);
    float inv = 1.0f / s;
#pragma unroll
    for (int i = 0; i < 16; ++i) {
        int q = i * 64 + lane;
        orow[q] = f2bf(e[i] * mmb[q] * inv);
    }
}

// ---------------- Wm bf16: Wm[bz][m=(c,u,v)][q] = b[c, 2qy+u-1, 2qx+v-1] ----------------
__global__ __launch_bounds__(256) void k_wm(const float* __restrict__ bsrc, unsigned short* __restrict__ Wm) {
    int idx = blockIdx.x * 256 + threadIdx.x;   // 2*2048*1024
    int q  = idx & (Lq - 1);
    int m  = (idx >> 10) & 2047;
    int bb = idx >> 21;
    int c = m >> 4, u = (m >> 2) & 3, v = m & 3;
    int qy = q >> 5, qx = q & 31;
    int y = 2 * qy + u - 1, x = 2 * qx + v - 1;
    float val = 0.f;
    if ((unsigned)y < 64u && (unsigned)x < 64u)
        val = bsrc[(((long)bb * CN + c) * 64 + y) * 64 + x];
    Wm[idx] = f2bf(val);
}

// ---------------- LDS-tiled MFMA GEMM: P[m][p] = sum_q Wm[m][q]*attnT[p][q] (r13-verified) ----------------
__global__ __launch_bounds__(256) void k_gemm_mfma(const unsigned short* __restrict__ WmA,
                                                   const unsigned short* __restrict__ At,
                                                   float* __restrict__ Cm) {
    const long bz = blockIdx.z;
    const unsigned short* A = WmA + bz * (2048L * Lq);
    const unsigned short* B = At  + bz * ((long)Lq * Lq);
    float* C = Cm + bz * (2048L * Lq);
    __shared__ __align__(16) unsigned short As[2048];
    __shared__ __align__(16) unsigned short Bs[2048];
    int t = threadIdx.x;
    int w = t >> 6, lane = t & 63;
    int quad = lane >> 4, l16 = lane & 15;
    int m0 = blockIdx.x * 64, n0 = blockIdx.y * 64;
    const unsigned short* aS = A + (long)(m0 + w * 16 + l16) * Lq + quad * 8;
    const unsigned short* bS = B + (long)(n0 + w * 16 + l16) * Lq + quad * 8;
    int sidx = w * 512 + quad * 128 + l16 * 8;
    int fidx = quad * 128 + l16 * 8;
    f32x4 acc0 = {0,0,0,0}, acc1 = {0,0,0,0}, acc2 = {0,0,0,0}, acc3 = {0,0,0,0};
    for (int k0 = 0; k0 < Lq; k0 += 32) {
        bf16x8 av = *(const bf16x8*)(aS + k0);      // issued before barrier: overlaps
        bf16x8 bv = *(const bf16x8*)(bS + k0);      // prior iteration's MFMAs
        __syncthreads();
        *(bf16x8*)&As[sidx] = av;
        *(bf16x8*)&Bs[sidx] = bv;
        __syncthreads();
        bf16x8 af = *(const bf16x8*)&As[w * 512 + fidx];
        bf16x8 b0 = *(const bf16x8*)&Bs[fidx];
        bf16x8 b1 = *(const bf16x8*)&Bs[512 + fidx];
        bf16x8 b2 = *(const bf16x8*)&Bs[1024 + fidx];
        bf16x8 b3 = *(const bf16x8*)&Bs[1536 + fidx];
        acc0 = __builtin_amdgcn_mfma_f32_16x16x32_bf16(af, b0, acc0, 0, 0, 0);
        acc1 = __builtin_amdgcn_mfma_f32_16x16x32_bf16(af, b1, acc1, 0, 0, 0);
        acc2 = __builtin_amdgcn_mfma_f32_16x16x32_bf16(af, b2, acc2, 0, 0, 0);
        acc3 = __builtin_amdgcn_mfma_f32_16x16x32_bf16(af, b3, acc3, 0, 0, 0);
    }
    int mrow = m0 + w * 16 + quad * 4;
#pragma unroll
    for (int r = 0; r < 4; ++r) {
        C[(long)(mrow + r) * Lq + n0 +  0 + l16] = acc0[r];
        C[(long)(mrow + r) * Lq + n0 + 16 + l16] = acc1[r];
        C[(long)(mrow + r) * Lq + n0 + 32 + l16] = acc2[r];
        C[(long)(mrow + r) * Lq + n0 + 48 + l16] = acc3[r];
    }
}

// ---------------- literal conv epilogue: fp32 tap-sum, /4, store fp32 (r11-verified) ----------------
__global__ __launch_bounds__(256) void k_epi2(const float* __restrict__ P, float* __restrict__ out) {
    int idx = blockIdx.x * 256 + threadIdx.x;   // 1048576
    int ox = idx & 63, oy = (idx >> 6) & 63, c = (idx >> 12) & 127, bb = idx >> 19;
    const float* Pb = P + (long)bb * 2048 * Lq;
    float s = 0.f;
#pragma unroll
    for (int u = 0; u < 4; ++u) {
        int t = oy + u - 2;
        if (t & 1) continue;
        int iy = t >> 1;
        if ((unsigned)iy >= (unsigned)HS) continue;
#pragma unroll
        for (int v = 0; v < 4; ++v) {
            int r = ox + v - 2;
            if (r & 1) continue;
            int ix = r >> 1;
            if ((unsigned)ix >= (unsigned)HS) continue;
            s += Pb[(long)((c << 4) + (3 - u) * 4 + (3 - v)) * Lq + (iy << 5) + ix];
        }
    }
    out[idx] = 0.25f * s;
}

extern "C" void kernel_launch(void* const* d_in, const int* in_sizes, int n_in,
                              void* d_out, int out_size, void* d_ws, size_t ws_size,
                              hipStream_t stream) {
    const float* f    = (const float*)d_in[0];
    const float* bsrc = (const float*)d_in[1];
    const float* mask = (const float*)d_in[2];
    float* out = (float*)d_out;
    float* ws = (float*)d_ws;

    // workspace (floats): ~9.18M = 36.7 MB
    float* bdT   = ws;                        // 262144
    float* ssq   = bdT   + 262144;            // 2048
    float* norms = ssq   + 2048;              // 2048
    float* mmb   = norms + 2048;              // 1024
    unsigned short* fH = (unsigned short*)(mmb + 1024);      // 262144 ushorts
    unsigned short* fL = fH + 262144;
    unsigned short* bH = fL + 262144;
    unsigned short* bL = bH + 262144;
    float* GTa   = (float*)(bL + 262144);     // 2097152 : GT -> attnT(bf16)
    float* C1    = GTa + 2097152;             // 2097152 : S0T -> P[0:2M]
    float* C2    = C1  + 2097152;             // 2097152 : S2T -> P[2M:4M]
    unsigned short* Wm = (unsigned short*)(C2 + 2097152);    // 4194304 ushorts
    float* S0T  = C1;
    float* S2T  = C2;
    unsigned short* attnT = (unsigned short*)GTa;  // GT dead after k_s0T
    float* P    = C1;      // spans C1+C2; S0T dead after fuse12, S2T dead after softmax

    hipLaunchKernelGGL(k_prep,      dim3(1024),       dim3(256), 0, stream, f, bsrc, bdT, fH, fL, bH, bL);
    hipLaunchKernelGGL(k_ssq,       dim3(2048),       dim3(64),  0, stream, bdT, ssq);
    hipLaunchKernelGGL(k_norms,     dim3(8),          dim3(256), 0, stream, ssq, norms);
    hipLaunchKernelGGL(k_mm,        dim3(4),          dim3(256), 0, stream, mask, mmb);
    hipLaunchKernelGGL(k_gram,      dim3(16, 16, 2),  dim3(256), 0, stream, fH, fL, bH, bL, GTa);
    hipLaunchKernelGGL(k_s0T,       dim3(8192),       dim3(256), 0, stream, GTa, norms, S0T);
    hipLaunchKernelGGL(k_fuse12,    dim3(8192),       dim3(256), 0, stream, S0T, S2T);
    hipLaunchKernelGGL(k_softmaxT,  dim3(512),        dim3(256), 0, stream, S2T, mmb, attnT);
    hipLaunchKernelGGL(k_wm,        dim3(16384),      dim3(256), 0, stream, bsrc, Wm);
    hipLaunchKernelGGL(k_gemm_mfma, dim3(32, 16, 2),  dim3(256), 0, stream, Wm, attnT, P);
    hipLaunchKernelGGL(k_epi2,      dim3(4096),       dim3(256), 0, stream, P, out);
}

// Round 15
// 160.229 us; speedup vs baseline: 2.4588x; 1.0315x over previous
//
#include <hip/hip_runtime.h>
#include <hip/hip_bf16.h>
#include <math.h>

constexpr int HS = 32;      // half spatial (32x32 grids)
constexpr int Lq = 1024;    // HS*HS
constexpr int CN = 128;     // channels
// batches = 2. Inputs fp32 (f, b, mask). Output fp32 (r11-verified).
// R15: k_gemm_mfma K-step 64 (half the barriers); prep+ssq merged (bdT dropped);
// norms+mm merged. Numerics identical to r14 (absmax 0.015625 expected).

typedef short bf16x8 __attribute__((ext_vector_type(8)));
typedef float f32x4  __attribute__((ext_vector_type(4)));

__device__ inline unsigned short f2bf(float x) {   // RNE float->bf16 bits
    union { float f; unsigned int u; } c; c.f = x;
    return (unsigned short)((c.u + 0x7FFF + ((c.u >> 16) & 1)) >> 16);
}
__device__ inline float bf2f(unsigned short h) {
    union { unsigned int u; float f; } c; c.u = ((unsigned int)h) << 16;
    return c.f;
}

// ---------------- merged prep+ssq: downsample, hi/lo bf16 splits, row ssq ----------------
// block = one (bb,p) row, 64 threads over channels (2 each). ssq from fp32 (matches r14).
__global__ __launch_bounds__(64) void k_prep2(const float* __restrict__ f,
                                              const float* __restrict__ bsrc,
                                              unsigned short* __restrict__ fH, unsigned short* __restrict__ fL,
                                              unsigned short* __restrict__ bH, unsigned short* __restrict__ bL,
                                              float* __restrict__ ssq) {
    int u = blockIdx.x;              // 0..2047 = bb*1024 + p
    int tx = threadIdx.x;            // 0..63
    int p = u & (Lq - 1), bb = u >> 10;
    int py = p >> 5, px = p & 31;
    long srcbase = (((long)bb * CN) * 64 + 2 * py) * 64 + 2 * px;
    float s = 0.f;
#pragma unroll
    for (int i = 0; i < 2; ++i) {
        int c = tx + i * 64;
        long src = srcbase + (long)c * 4096;
        float fv = f[src], bv = bsrc[src];
        int o = u * CN + c;
        unsigned short fh = f2bf(fv), bh = f2bf(bv);
        fH[o] = fh; fL[o] = f2bf(fv - bf2f(fh));
        bH[o] = bh; bL[o] = f2bf(bv - bf2f(bh));
        s += bv * bv;
    }
    for (int off = 32; off > 0; off >>= 1) s += __shfl_down(s, off, 64);
    if (tx == 0) ssq[u] = s;
}

// ---------------- merged norms+mm: idx<2048 -> norms; else mm[idx-2048] ----------------
__global__ __launch_bounds__(256) void k_nm(const float* __restrict__ ssq, const float* __restrict__ mask,
                                            float* __restrict__ norms, float* __restrict__ mmb) {
    int idx = blockIdx.x * 256 + threadIdx.x;   // 0..3071
    if (idx < 2048) {
        int q = idx & (Lq - 1);
        int bb = idx >> 10;
        int qy = q >> 5, qx = q & 31;
        float s = 0.1152f;
        for (int dk = -1; dk <= 1; ++dk) {
            int y = qy + dk; if ((unsigned)y >= (unsigned)HS) continue;
            for (int dl = -1; dl <= 1; ++dl) {
                int x = qx + dl; if ((unsigned)x >= (unsigned)HS) continue;
                s += ssq[bb * Lq + y * HS + x];
            }
        }
        norms[idx] = sqrtf(s);
    } else {
        int q = idx - 2048;                      // 0..1023
        int qy = q >> 5, qx = q & 31;
        float s = 0.f;
        for (int dk = -1; dk <= 1; ++dk) {
            int y = qy + dk; if ((unsigned)y >= (unsigned)HS) continue;
            for (int dl = -1; dl <= 1; ++dl) {
                int x = qx + dl; if ((unsigned)x >= (unsigned)HS) continue;
                s += mask[(8 * y) * 256 + 8 * x];
            }
        }
        mmb[q] = (s == 0.0f) ? 1.0f : 0.0f;
    }
}

// ---------------- Gram MFMA bf16x2: GT[p'][q'] = sum_c fd[p'][c]*bd[q'][c] (r14-verified) ----------------
__global__ __launch_bounds__(256) void k_gram(const unsigned short* __restrict__ fH,
                                              const unsigned short* __restrict__ fL,
                                              const unsigned short* __restrict__ bH,
                                              const unsigned short* __restrict__ bL,
                                              float* __restrict__ GT) {
    const long bz = blockIdx.z;
    const unsigned short* AH = fH + bz * 131072;
    const unsigned short* AL = fL + bz * 131072;
    const unsigned short* BH = bH + bz * 131072;
    const unsigned short* BL = bL + bz * 131072;
    float* C = GT + (bz << 20);
    int t = threadIdx.x, w = t >> 6, lane = t & 63, quad = lane >> 4, l16 = lane & 15;
    int wm = blockIdx.x * 64 + (w & 1) * 32;
    int wn = blockIdx.y * 64 + (w >> 1) * 32;
    int ko = quad * 8;
    f32x4 acc[2][2] = {};
#pragma unroll
    for (int k0 = 0; k0 < 128; k0 += 32) {
        bf16x8 ah0 = *(const bf16x8*)&AH[(wm + l16) * 128 + ko + k0];
        bf16x8 ah1 = *(const bf16x8*)&AH[(wm + 16 + l16) * 128 + ko + k0];
        bf16x8 al0 = *(const bf16x8*)&AL[(wm + l16) * 128 + ko + k0];
        bf16x8 al1 = *(const bf16x8*)&AL[(wm + 16 + l16) * 128 + ko + k0];
        bf16x8 bh0 = *(const bf16x8*)&BH[(wn + l16) * 128 + ko + k0];
        bf16x8 bh1 = *(const bf16x8*)&BH[(wn + 16 + l16) * 128 + ko + k0];
        bf16x8 bl0 = *(const bf16x8*)&BL[(wn + l16) * 128 + ko + k0];
        bf16x8 bl1 = *(const bf16x8*)&BL[(wn + 16 + l16) * 128 + ko + k0];
        acc[0][0] = __builtin_amdgcn_mfma_f32_16x16x32_bf16(ah0, bh0, acc[0][0], 0, 0, 0);
        acc[0][1] = __builtin_amdgcn_mfma_f32_16x16x32_bf16(ah0, bh1, acc[0][1], 0, 0, 0);
        acc[1][0] = __builtin_amdgcn_mfma_f32_16x16x32_bf16(ah1, bh0, acc[1][0], 0, 0, 0);
        acc[1][1] = __builtin_amdgcn_mfma_f32_16x16x32_bf16(ah1, bh1, acc[1][1], 0, 0, 0);
        acc[0][0] = __builtin_amdgcn_mfma_f32_16x16x32_bf16(ah0, bl0, acc[0][0], 0, 0, 0);
        acc[0][1] = __builtin_amdgcn_mfma_f32_16x16x32_bf16(ah0, bl1, acc[0][1], 0, 0, 0);
        acc[1][0] = __builtin_amdgcn_mfma_f32_16x16x32_bf16(ah1, bl0, acc[1][0], 0, 0, 0);
        acc[1][1] = __builtin_amdgcn_mfma_f32_16x16x32_bf16(ah1, bl1, acc[1][1], 0, 0, 0);
        acc[0][0] = __builtin_amdgcn_mfma_f32_16x16x32_bf16(al0, bh0, acc[0][0], 0, 0, 0);
        acc[0][1] = __builtin_amdgcn_mfma_f32_16x16x32_bf16(al0, bh1, acc[0][1], 0, 0, 0);
        acc[1][0] = __builtin_amdgcn_mfma_f32_16x16x32_bf16(al1, bh0, acc[1][0], 0, 0, 0);
        acc[1][1] = __builtin_amdgcn_mfma_f32_16x16x32_bf16(al1, bh1, acc[1][1], 0, 0, 0);
    }
#pragma unroll
    for (int i = 0; i < 2; ++i)
#pragma unroll
        for (int j = 0; j < 2; ++j) {
            int mrow = wm + i * 16 + quad * 4;
            int ncol = wn + j * 16 + l16;
#pragma unroll
            for (int r = 0; r < 4; ++r)
                C[(long)(mrow + r) * Lq + ncol] = acc[i][j][r];
        }
}

// ---------------- S0T[p][q] = band9(GT) / norms[q]  (T-layout, r14-verified) ----------------
__global__ __launch_bounds__(256) void k_s0T(const float* __restrict__ GT, const float* __restrict__ norms,
                                             float* __restrict__ S0T) {
    int idx = blockIdx.x * 256 + threadIdx.x;  // 2*1024*1024
    int q  = idx & (Lq - 1);
    int pp = (idx >> 10) & (Lq - 1);
    int bb = idx >> 20;
    int qy = q >> 5, qx = q & 31, py = pp >> 5, px = pp & 31;
    const float* Gb = GT + ((long)bb << 20);
    float s = 0.f;
#pragma unroll
    for (int dk = -1; dk <= 1; ++dk) {
        if ((unsigned)(qy + dk) >= (unsigned)HS || (unsigned)(py + dk) >= (unsigned)HS) continue;
#pragma unroll
        for (int dl = -1; dl <= 1; ++dl) {
            if ((unsigned)(qx + dl) >= (unsigned)HS || (unsigned)(px + dl) >= (unsigned)HS) continue;
            int sft = dk * HS + dl;
            s += Gb[(long)(pp + sft) * Lq + (q + sft)];
        }
    }
    S0T[idx] = s / norms[bb * Lq + q];
}

// ---------------- FUSED fuse1+fuse2 on T layout (r14-verified) ----------------
__global__ __launch_bounds__(256) void k_fuse12(const float* __restrict__ S0, float* __restrict__ S2) {
    int idx = blockIdx.x * 256 + threadIdx.x;   // 2*1024*1024
    int p  = idx & (Lq - 1);
    int q  = (idx >> 10) & (Lq - 1);
    int bb = idx >> 20;
    int hb = q >> 5, wb = q & 31, hf = p >> 5, wf = p & 31;
    int ip = wb * HS + hb, jp = wf * HS + hf;
    const float* S = S0 + (long)bb * Lq * Lq;
    float s = 0.f;
#pragma unroll
    for (int d = -1; d <= 1; ++d) {
        int t = ip + d, r = jp + d;
        if ((unsigned)t < (unsigned)Lq && (unsigned)r < (unsigned)Lq) {
            int q2 = (t & 31) * HS + (t >> 5);
            int p2 = (r & 31) * HS + (r >> 5);
            long base = (long)q2 * Lq + p2;
            float v = S[base];
            if (q2 > 0 && p2 > 0)             v += S[base - (Lq + 1)];
            if (q2 < Lq - 1 && p2 < Lq - 1)   v += S[base + (Lq + 1)];
            s += v;
        }
    }
    S2[idx] = s;
}

// ---------------- row softmax over q on S2T[p][q]; writes attnT bf16 [p][q] (r13-verified) ----------------
__global__ __launch_bounds__(256) void k_softmaxT(const float* __restrict__ S2T, const float* __restrict__ mmb,
                                                  unsigned short* __restrict__ At) {
    int wid = blockIdx.x * 4 + (threadIdx.x >> 6);   // 0..2047
    int lane = threadIdx.x & 63;
    int bb = wid >> 10, p = wid & (Lq - 1);
    const float* row = S2T + ((long)bb << 20) + (long)p * Lq;
    unsigned short* orow = At + ((long)bb << 20) + (long)p * Lq;
    float x[16]; float mx = -1e30f;
#pragma unroll
    for (int i = 0; i < 16; ++i) {
        int q = i * 64 + lane;
        x[i] = row[q] * mmb[q] * 10.0f;
        mx = fmaxf(mx, x[i]);
    }
    for (int off = 32; off > 0; off >>= 1) mx = fmaxf(mx, __shfl_xor(mx, off, 64));
    float e[16]; float s = 0.f;
#pragma unroll
    for (int i = 0; i < 16; ++i) { e[i] = __expf(x[i] - mx); s += e[i]; }
    for (int off = 32; off > 0; off >>= 1) s += __shfl_xor(s, off, 64);
    float inv = 1.0f / s;
#pragma unroll
    for (int i = 0; i < 16; ++i) {
        int q = i * 64 + lane;
        orow[q] = f2bf(e[i] * mmb[q] * inv);
    }
}

// ---------------- Wm bf16: Wm[bz][m=(c,u,v)][q] = b[c, 2qy+u-1, 2qx+v-1] (r13-verified) ----------------
__global__ __launch_bounds__(256) void k_wm(const float* __restrict__ bsrc, unsigned short* __restrict__ Wm) {
    int idx = blockIdx.x * 256 + threadIdx.x;   // 2*2048*1024
    int q  = idx & (Lq - 1);
    int m  = (idx >> 10) & 2047;
    int bb = idx >> 21;
    int c = m >> 4, u = (m >> 2) & 3, v = m & 3;
    int qy = q >> 5, qx = q & 31;
    int y = 2 * qy + u - 1, x = 2 * qx + v - 1;
    float val = 0.f;
    if ((unsigned)y < 64u && (unsigned)x < 64u)
        val = bsrc[(((long)bb * CN + c) * 64 + y) * 64 + x];
    Wm[idx] = f2bf(val);
}

// ---------------- LDS-tiled MFMA GEMM, K-step 64: P[m][p] = sum_q Wm[m][q]*attnT[p][q] ----------------
// 64x64 tile, 4 waves; per step: stage 2x32-k slabs of A and B, 8 MFMAs/wave between barriers.
// Frag math identical to r13/r14 (HW-verified).
__global__ __launch_bounds__(256) void k_gemm_mfma(const unsigned short* __restrict__ WmA,
                                                   const unsigned short* __restrict__ At,
                                                   float* __restrict__ Cm) {
    const long bz = blockIdx.z;
    const unsigned short* A = WmA + bz * (2048L * Lq);
    const unsigned short* B = At  + bz * ((long)Lq * Lq);
    float* C = Cm + bz * (2048L * Lq);
    __shared__ __align__(16) unsigned short As[4096];
    __shared__ __align__(16) unsigned short Bs[4096];
    int t = threadIdx.x;
    int w = t >> 6, lane = t & 63;
    int quad = lane >> 4, l16 = lane & 15;
    int m0 = blockIdx.x * 64, n0 = blockIdx.y * 64;
    const unsigned short* aS = A + (long)(m0 + w * 16 + l16) * Lq + quad * 8;
    const unsigned short* bS = B + (long)(n0 + w * 16 + l16) * Lq + quad * 8;
    int sidx = w * 512 + quad * 128 + l16 * 8;
    int fidx = quad * 128 + l16 * 8;
    f32x4 acc0 = {0,0,0,0}, acc1 = {0,0,0,0}, acc2 = {0,0,0,0}, acc3 = {0,0,0,0};
    for (int k0 = 0; k0 < Lq; k0 += 64) {
        bf16x8 av0 = *(const bf16x8*)(aS + k0);
        bf16x8 av1 = *(const bf16x8*)(aS + k0 + 32);
        bf16x8 bv0 = *(const bf16x8*)(bS + k0);
        bf16x8 bv1 = *(const bf16x8*)(bS + k0 + 32);
        __syncthreads();
        *(bf16x8*)&As[sidx]        = av0;
        *(bf16x8*)&As[2048 + sidx] = av1;
        *(bf16x8*)&Bs[sidx]        = bv0;
        *(bf16x8*)&Bs[2048 + sidx] = bv1;
        __syncthreads();
#pragma unroll
        for (int kc = 0; kc < 2; ++kc) {
            int o = kc * 2048;
            bf16x8 af = *(const bf16x8*)&As[o + w * 512 + fidx];
            bf16x8 b0 = *(const bf16x8*)&Bs[o + fidx];
            bf16x8 b1 = *(const bf16x8*)&Bs[o + 512 + fidx];
            bf16x8 b2 = *(const bf16x8*)&Bs[o + 1024 + fidx];
            bf16x8 b3 = *(const bf16x8*)&Bs[o + 1536 + fidx];
            acc0 = __builtin_amdgcn_mfma_f32_16x16x32_bf16(af, b0, acc0, 0, 0, 0);
            acc1 = __builtin_amdgcn_mfma_f32_16x16x32_bf16(af, b1, acc1, 0, 0, 0);
            acc2 = __builtin_amdgcn_mfma_f32_16x16x32_bf16(af, b2, acc2, 0, 0, 0);
            acc3 = __builtin_amdgcn_mfma_f32_16x16x32_bf16(af, b3, acc3, 0, 0, 0);
        }
    }
    int mrow = m0 + w * 16 + quad * 4;
#pragma unroll
    for (int r = 0; r < 4; ++r) {
        C[(long)(mrow + r) * Lq + n0 +  0 + l16] = acc0[r];
        C[(long)(mrow + r) * Lq + n0 + 16 + l16] = acc1[r];
        C[(long)(mrow + r) * Lq + n0 + 32 + l16] = acc2[r];
        C[(long)(mrow + r) * Lq + n0 + 48 + l16] = acc3[r];
    }
}

// ---------------- literal conv epilogue: fp32 tap-sum, /4, store fp32 (r11-verified) ----------------
__global__ __launch_bounds__(256) void k_epi2(const float* __restrict__ P, float* __restrict__ out) {
    int idx = blockIdx.x * 256 + threadIdx.x;   // 1048576
    int ox = idx & 63, oy = (idx >> 6) & 63, c = (idx >> 12) & 127, bb = idx >> 19;
    const float* Pb = P + (long)bb * 2048 * Lq;
    float s = 0.f;
#pragma unroll
    for (int u = 0; u < 4; ++u) {
        int t = oy + u - 2;
        if (t & 1) continue;
        int iy = t >> 1;
        if ((unsigned)iy >= (unsigned)HS) continue;
#pragma unroll
        for (int v = 0; v < 4; ++v) {
            int r = ox + v - 2;
            if (r & 1) continue;
            int ix = r >> 1;
            if ((unsigned)ix >= (unsigned)HS) continue;
            s += Pb[(long)((c << 4) + (3 - u) * 4 + (3 - v)) * Lq + (iy << 5) + ix];
        }
    }
    out[idx] = 0.25f * s;
}

extern "C" void kernel_launch(void* const* d_in, const int* in_sizes, int n_in,
                              void* d_out, int out_size, void* d_ws, size_t ws_size,
                              hipStream_t stream) {
    const float* f    = (const float*)d_in[0];
    const float* bsrc = (const float*)d_in[1];
    const float* mask = (const float*)d_in[2];
    float* out = (float*)d_out;
    float* ws = (float*)d_ws;

    // workspace (floats): ~8.92M = 35.7 MB
    float* ssq   = ws;                        // 2048
    float* norms = ssq   + 2048;              // 2048
    float* mmb   = norms + 2048;              // 1024
    unsigned short* fH = (unsigned short*)(mmb + 1024);      // 262144 ushorts each
    unsigned short* fL = fH + 262144;
    unsigned short* bH = fL + 262144;
    unsigned short* bL = bH + 262144;
    float* GTa   = (float*)(bL + 262144);     // 2097152 : GT -> attnT(bf16)
    float* C1    = GTa + 2097152;             // 2097152 : S0T -> P[0:2M]
    float* C2    = C1  + 2097152;             // 2097152 : S2T -> P[2M:4M]
    unsigned short* Wm = (unsigned short*)(C2 + 2097152);    // 4194304 ushorts
    float* S0T  = C1;
    float* S2T  = C2;
    unsigned short* attnT = (unsigned short*)GTa;  // GT dead after k_s0T
    float* P    = C1;      // spans C1+C2; S0T dead after fuse12, S2T dead after softmax

    hipLaunchKernelGGL(k_prep2,     dim3(2048),       dim3(64),  0, stream, f, bsrc, fH, fL, bH, bL, ssq);
    hipLaunchKernelGGL(k_nm,        dim3(12),         dim3(256), 0, stream, ssq, mask, norms, mmb);
    hipLaunchKernelGGL(k_gram,      dim3(16, 16, 2),  dim3(256), 0, stream, fH, fL, bH, bL, GTa);
    hipLaunchKernelGGL(k_s0T,       dim3(8192),       dim3(256), 0, stream, GTa, norms, S0T);
    hipLaunchKernelGGL(k_fuse12,    dim3(8192),       dim3(256), 0, stream, S0T, S2T);
    hipLaunchKernelGGL(k_softmaxT,  dim3(512),        dim3(256), 0, stream, S2T, mmb, attnT);
    hipLaunchKernelGGL(k_wm,        dim3(16384),      dim3(256), 0, stream, bsrc, Wm);
    hipLaunchKernelGGL(k_gemm_mfma, dim3(32, 16, 2),  dim3(256), 0, stream, Wm, attnT, P);
    hipLaunchKernelGGL(k_epi2,      dim3(4096),       dim3(256), 0, stream, P, out);
}